// Round 1
// 499.229 us; speedup vs baseline: 1.0630x; 1.0630x over previous
//
#include <hip/hip_runtime.h>

#define DIM 2048
#define NB 8
#define NT (DIM / 64)   // K-tiles of 64 in the 256^2 8-phase kernel

typedef _Float16 f16;
typedef __attribute__((ext_vector_type(8))) _Float16 f16x8;
typedef __attribute__((ext_vector_type(4))) _Float16 f16x4;
typedef __attribute__((ext_vector_type(2))) _Float16 f16x2;
typedef __attribute__((ext_vector_type(4))) float f32x4;
typedef __attribute__((ext_vector_type(4))) unsigned u32x4;

// ---- float <-> orderable uint key (for atomicMax on floats) ----
__device__ __forceinline__ unsigned fkey(float f) {
    unsigned u = __float_as_uint(f);
    return (u & 0x80000000u) ? ~u : (u | 0x80000000u);
}
__device__ __forceinline__ float fdecode(unsigned k) {
    return (k & 0x80000000u) ? __uint_as_float(k ^ 0x80000000u)
                             : __uint_as_float(~k);
}

// ---- async global->LDS 16B DMA (dest = wave-uniform base + lane*16) ----
__device__ __forceinline__ void gld_lds16(const f16* g, f16* l) {
    __builtin_amdgcn_global_load_lds(
        (const __attribute__((address_space(1))) unsigned*)g,
        (__attribute__((address_space(3))) unsigned*)l, 16, 0, 0);
}

// ---- raw barrier / counted waitcnt discipline (8-phase schedule) ----
#define BAR() asm volatile("s_barrier" ::: "memory")
#define WAITLGKM0()                                            \
    do {                                                       \
        asm volatile("s_waitcnt lgkmcnt(0)" ::: "memory");     \
        __builtin_amdgcn_sched_barrier(0);                     \
    } while (0)
#define WAITVM(N) asm volatile("s_waitcnt vmcnt(" #N ")" ::: "memory")

// ---- fp32 -> fp16 conversion, float4 vectorized ----
__global__ __launch_bounds__(256) void k_convert(const float* __restrict__ src,
                                                 f16* __restrict__ dst, int n4) {
    int i = blockIdx.x * 256 + threadIdx.x;
    if (i >= n4) return;
    f32x4 v = ((const f32x4*)src)[i];
    ((f16x4*)dst)[i] = __builtin_convertvector(v, f16x4);
}

// ---- fused: fp32->fp16 convert of x AND column sums over token axis ----
__global__ __launch_bounds__(256) void k_prep(const float* __restrict__ x,
                                              f16* __restrict__ Xf,
                                              float* __restrict__ vsum) {
    const int b  = blockIdx.z;
    const int c0 = blockIdx.x * 1024 + threadIdx.x * 4;
    const int n0 = blockIdx.y * 64;
    const float* px = x  + ((size_t)b * DIM + n0) * DIM + c0;
    f16*         pd = Xf + ((size_t)b * DIM + n0) * DIM + c0;
    f32x4 s = (f32x4){0.f, 0.f, 0.f, 0.f};
    #pragma unroll 8
    for (int n = 0; n < 64; ++n) {
        f32x4 v = *(const f32x4*)(px + (size_t)n * DIM);
        *(f16x4*)(pd + (size_t)n * DIM) = __builtin_convertvector(v, f16x4);
        s += v;
    }
    atomicAdd(&vsum[b * DIM + c0 + 0], s.x);
    atomicAdd(&vsum[b * DIM + c0 + 1], s.y);
    atomicAdd(&vsum[b * DIM + c0 + 2], s.z);
    atomicAdd(&vsum[b * DIM + c0 + 3], s.w);
}

// ---- column sums of x over token axis (fallback paths only) ----
__global__ __launch_bounds__(256) void k_colsum(const float* __restrict__ x,
                                                float* __restrict__ vsum) {
    int b = blockIdx.z;
    int c = blockIdx.x * 256 + threadIdx.x;
    int n0 = blockIdx.y * (DIM / 8);
    const float* p = x + ((size_t)b * DIM + n0) * DIM + c;
    float s = 0.f;
    #pragma unroll 8
    for (int n = 0; n < DIM / 8; ++n) s += p[(size_t)n * DIM];
    atomicAdd(&vsum[b * DIM + c], s);
}

// ---- 128x128 tile core (kept for k_gram): C = A @ Bt^T, f16 ----
__device__ __forceinline__ void gemm128_core(const f16* __restrict__ A,
                                             const f16* __restrict__ Bt,
                                             int br, int bc,
                                             f16* As, f16* Bs,
                                             f32x4 acc[4][4]) {
    const int tid  = threadIdx.x;
    const int ln   = tid & 63;
    const int wv   = tid >> 6;
    const int l15  = ln & 15;
    const int quad = ln >> 4;
    const int wr   = (wv >> 1) * 64;
    const int wc   = (wv & 1) * 64;
    const int lrow = ln >> 3;
    const int lg   = (ln & 7) ^ lrow;
    const int swz  = l15 & 7;

    const f16* gA = A  + (size_t)(br * 128 + wv * 32 + lrow) * DIM + lg * 8;
    const f16* gB = Bt + (size_t)(bc * 128 + wv * 32 + lrow) * DIM + lg * 8;
    f16* lA = As + wv * 2048 + ln * 8;
    f16* lB = Bs + wv * 2048 + ln * 8;

    #pragma unroll
    for (int i = 0; i < 4; ++i)
        #pragma unroll
        for (int j = 0; j < 4; ++j)
            acc[i][j] = (f32x4){0.f, 0.f, 0.f, 0.f};

    for (int kt = 0; kt < DIM / 64; ++kt) {
        __syncthreads();
        #pragma unroll
        for (int u = 0; u < 4; ++u) {
            gld_lds16(gA + (size_t)u * 8 * DIM, lA + u * 512);
            gld_lds16(gB + (size_t)u * 8 * DIM, lB + u * 512);
        }
        gA += 64; gB += 64;
        __syncthreads();
        #pragma unroll
        for (int kk = 0; kk < 2; ++kk) {
            const int s = (kk * 4 + quad) ^ swz;
            f16x8 af[4], bf[4];
            #pragma unroll
            for (int i = 0; i < 4; ++i)
                af[i] = *(const f16x8*)(As + (wr + i * 16 + l15) * 64 + s * 8);
            #pragma unroll
            for (int j = 0; j < 4; ++j)
                bf[j] = *(const f16x8*)(Bs + (wc + j * 16 + l15) * 64 + s * 8);
            #pragma unroll
            for (int i = 0; i < 4; ++i)
                #pragma unroll
                for (int j = 0; j < 4; ++j)
                    acc[i][j] = __builtin_amdgcn_mfma_f32_16x16x32_f16(af[i], bf[j], acc[i][j], 0, 0, 0);
        }
    }
}

// ---- Gram: G_b = X_b @ X_b^T (symmetric; triangular grid, LDS-transposed mirror) ----
__global__ __launch_bounds__(256) void k_gram(const f16* __restrict__ Xall,
                                              f16* __restrict__ Gall,
                                              unsigned long xStride,
                                              unsigned long gStride) {
    const int b = blockIdx.y;
    const f16* X = Xall + (size_t)b * xStride;
    f16* G = Gall + (size_t)b * gStride;

    int t = blockIdx.x;
    int br = (int)((sqrtf(8.f * t + 1.f) - 1.f) * 0.5f);
    while ((br + 1) * (br + 2) / 2 <= t) ++br;
    while (br * (br + 1) / 2 > t) --br;
    int bc = t - br * (br + 1) / 2;

    __shared__ __align__(16) f16 smem[128 * 136];
    f16* As = smem;
    f16* Bs = smem + 8192;
    f32x4 acc[4][4];
    gemm128_core(X, X, br, bc, As, Bs, acc);

    const int tid = threadIdx.x;
    const int ln = tid & 63;
    const int wv = tid >> 6;
    const int wr = (wv >> 1) * 64, wc = (wv & 1) * 64;
    const int l15 = ln & 15, quad = ln >> 4;

    #pragma unroll
    for (int i = 0; i < 4; ++i)
        #pragma unroll
        for (int j = 0; j < 4; ++j)
            #pragma unroll
            for (int r = 0; r < 4; ++r) {
                int row = br * 128 + wr + i * 16 + quad * 4 + r;
                int col = bc * 128 + wc + j * 16 + l15;
                G[(size_t)row * DIM + col] = (f16)acc[i][j][r];
            }

    if (br != bc) {
        __syncthreads();
        f16* T = smem;
        #pragma unroll
        for (int i = 0; i < 4; ++i)
            #pragma unroll
            for (int j = 0; j < 4; ++j)
                #pragma unroll
                for (int h = 0; h < 2; ++h) {
                    int row = wr + i * 16 + quad * 4 + h * 2;
                    int col = wc + j * 16 + l15;
                    f16x2 v = {(f16)acc[i][j][h * 2], (f16)acc[i][j][h * 2 + 1]};
                    *(f16x2*)(T + col * 136 + row) = v;
                }
        __syncthreads();
        #pragma unroll
        for (int p = 0; p < 8; ++p) {
            int ch = p * 256 + tid;
            int rt = ch >> 4, seg = ch & 15;
            f16x8 v = *(const f16x8*)(T + rt * 136 + seg * 8);
            *(f16x8*)(G + (size_t)(bc * 128 + rt) * DIM + br * 128 + seg * 8) = v;
        }
    }
}

// ---- attn tile = scale * Wq @ G_b  (256^2 tile, BK=64, 8 waves, 8-phase
//      counted-vmcnt schedule; fused row-max via shfl + atomicMax) ----
__global__ __launch_bounds__(512, 2)
void k_attn256(const f16* __restrict__ Wq, const f16* __restrict__ Gall,
               unsigned* __restrict__ mkey, unsigned long gStride, int batchBase) {
    __shared__ __align__(16) f16 sm[2][2][256 * 64];   // [buf][op A/B][row*chunk] = 128 KiB

    const int q  = gridDim.x >> 3;
    const int w  = (blockIdx.x & 7) * q + (blockIdx.x >> 3);   // XCD-chunked, bijective
    const int zi = w >> 6;
    const int br = (w >> 3) & 7;
    const int bc = w & 7;
    const f16* A  = Wq;
    const f16* Bt = Gall + (size_t)zi * gStride;   // G symmetric: rows serve as Bt rows
    const int bi = batchBase + zi;

    const int tid  = threadIdx.x;
    const int ln   = tid & 63;
    const int wv   = tid >> 6;
    const int wm   = wv >> 2;
    const int wn   = wv & 3;
    const int l15  = ln & 15;
    const int quad = ln >> 4;
    const int swz  = l15 & 7;
    const int cc0  = ((quad) ^ swz) * 8;
    const int cc1  = ((4 | quad) ^ swz) * 8;
    const int lrow = ln >> 3;
    const int lchunk = (ln & 7) ^ lrow;

    f32x4 acc[8][4];
    #pragma unroll
    for (int i = 0; i < 8; ++i)
        #pragma unroll
        for (int j = 0; j < 4; ++j) acc[i][j] = (f32x4){0.f, 0.f, 0.f, 0.f};

    auto stage = [&](int t, int s) {
        if (t >= NT) return;
        const int p = t & 1;
        const f16* src; int rowb; f16* L;
        if (s == 0 || s == 3) { src = A;  rowb = br * 256; L = (f16*)sm[p][0]; }
        else                  { src = Bt; rowb = bc * 256; L = (f16*)sm[p][1]; }
        const int h  = (s >= 2) ? 1 : 0;
        const int r0 = h * 128 + wv * 16;
        const f16* gp = src + (size_t)(rowb + r0 + lrow) * DIM + t * 64 + lchunk * 8;
        f16* lp = L + r0 * 64 + ln * 8;
        gld_lds16(gp, lp);
        gld_lds16(gp + (size_t)8 * DIM, lp + 512);
    };

    f16x8 af[4][2], bl[2][2], bh[2][2];

    auto loadA = [&](int qm, const f16* LA) {
        #pragma unroll
        for (int i = 0; i < 4; ++i) {
            const f16* pa = LA + (qm * 128 + wm * 64 + i * 16 + l15) * 64;
            af[i][0] = *(const f16x8*)(pa + cc0);
            af[i][1] = *(const f16x8*)(pa + cc1);
        }
    };
    auto loadB = [&](int qn, const f16* LB, f16x8 (&bf)[2][2]) {
        #pragma unroll
        for (int j = 0; j < 2; ++j) {
            const f16* pb = LB + (qn * 128 + wn * 32 + j * 16 + l15) * 64;
            bf[j][0] = *(const f16x8*)(pb + cc0);
            bf[j][1] = *(const f16x8*)(pb + cc1);
        }
    };
    auto mfmaQ = [&](int qm, int qn, f16x8 (&a)[4][2], f16x8 (&bf)[2][2]) {
        __builtin_amdgcn_s_setprio(1);
        #pragma unroll
        for (int i = 0; i < 4; ++i)
            #pragma unroll
            for (int j = 0; j < 2; ++j)
                #pragma unroll
                for (int kk = 0; kk < 2; ++kk)
                    acc[qm * 4 + i][qn * 2 + j] = __builtin_amdgcn_mfma_f32_16x16x32_f16(
                        a[i][kk], bf[j][kk], acc[qm * 4 + i][qn * 2 + j], 0, 0, 0);
        __builtin_amdgcn_s_setprio(0);
        __builtin_amdgcn_sched_barrier(0);
    };

    stage(0, 0); stage(0, 1); stage(0, 2); stage(0, 3);
    WAITVM(4);
    stage(1, 0); stage(1, 1); stage(1, 2);
    WAITVM(6);
    BAR();

    for (int t = 0; t < NT; ++t) {
        const int p = t & 1;
        const f16* LA = (const f16*)sm[p][0];
        const f16* LB = (const f16*)sm[p][1];
        // P0: (A-low, B-low)
        loadA(0, LA); loadB(0, LB, bl);
        stage(t + 1, 3);
        BAR(); WAITLGKM0();
        mfmaQ(0, 0, af, bl);
        BAR();
        // P1: (A-low, B-high)
        loadB(1, LB, bh);
        stage(t + 2, 0);
        BAR(); WAITLGKM0();
        mfmaQ(0, 1, af, bh);
        BAR();
        // P2: (A-high, B-high)
        loadA(1, LA);
        stage(t + 2, 1);
        BAR(); WAITLGKM0();
        mfmaQ(1, 1, af, bh);
        BAR();
        // P3: (A-high, B-low) -- B-low held in regs (its LDS slot restaged in P2)
        stage(t + 2, 2);
        BAR();
        mfmaQ(1, 0, af, bl);
        if (t < NT - 2) { WAITVM(6); }
        else            { WAITVM(0); }
        BAR();
    }

    const float scale = 0.0625f;              // (2048/8)^-0.5
    #pragma unroll
    for (int i = 0; i < 8; ++i) {
        const int qm = i >> 2, il = i & 3;
        #pragma unroll
        for (int r = 0; r < 4; ++r) {
            float v = fmaxf(fmaxf(acc[i][0][r], acc[i][1][r]),
                            fmaxf(acc[i][2][r], acc[i][3][r]));
            #pragma unroll
            for (int m = 1; m <= 8; m <<= 1)
                v = fmaxf(v, __shfl_xor(v, m, 64));
            if (l15 == 0) {
                const int row = br * 256 + qm * 128 + wm * 64 + il * 16 + quad * 4 + r;
                atomicMax(&mkey[(size_t)bi * DIM + row], fkey(scale * v));
            }
        }
    }
}

// ---- out[b,i,j] = (vsum[b,i]/2048) * m[b,j] ----
__global__ __launch_bounds__(256) void k_final(const float* __restrict__ vsum,
                                               const unsigned* __restrict__ mkey,
                                               float* __restrict__ out) {
    int gid = blockIdx.x * 256 + threadIdx.x;
    int b   = gid >> 20;
    int rem = gid & 1048575;
    int i   = rem >> 9;
    int jq  = rem & 511;
    float v = vsum[(b << 11) + i] * (1.f / 2048.f);
    u32x4 k = ((const u32x4*)mkey)[(b << 9) + jq];
    f32x4 o;
    o.x = v * fdecode(k.x);
    o.y = v * fdecode(k.y);
    o.z = v * fdecode(k.z);
    o.w = v * fdecode(k.w);
    ((f32x4*)out)[gid] = o;
}

extern "C" void kernel_launch(void* const* d_in, const int* in_sizes, int n_in,
                              void* d_out, int out_size, void* d_ws, size_t ws_size,
                              hipStream_t stream) {
    const float* x  = (const float*)d_in[0];
    const float* Wq = (const float*)d_in[1];
    float* out = (float*)d_out;
    char* ws = (char*)d_ws;

    const size_t elems = (size_t)DIM * DIM;
    unsigned* mkey = (unsigned*)ws;                         // 64 KB
    float*    vsum = (float*)(ws + 65536);                  // 64 KB
    f16*      Wqf  = (f16*)(ws + 131072);                   // 8 MB
    f16*      Xf   = (f16*)(ws + 131072 + elems * 2);

    const size_t need1 = 131072 + elems * 2 * (1 + NB + NB);  // ~142.7 MB
    const size_t need2 = 131072 + elems * 2 * (1 + NB + 1);   // ~84.0 MB

    hipMemsetAsync(ws, 0, 131072, stream);
    k_convert<<<4096, 256, 0, stream>>>(Wq, Wqf, (int)(elems / 4));

    if (ws_size >= need1) {
        f16* G = Xf + NB * elems;
        k_prep<<<dim3(2, 32, NB), 256, 0, stream>>>(x, Xf, vsum);
        k_gram<<<dim3(136, NB), 256, 0, stream>>>(Xf, G, elems, elems);
        k_attn256<<<dim3(512), 512, 0, stream>>>(Wqf, G, mkey, elems, 0);
    } else if (ws_size >= need2) {
        f16* G = Xf + NB * elems;
        k_prep<<<dim3(2, 32, NB), 256, 0, stream>>>(x, Xf, vsum);
        for (int b = 0; b < NB; ++b) {
            k_gram<<<dim3(136, 1), 256, 0, stream>>>(Xf + (size_t)b * elems, G, 0, 0);
            k_attn256<<<dim3(64), 512, 0, stream>>>(Wqf, G, mkey, 0, b);
        }
    } else {
        f16* G = Xf + elems;
        k_colsum<<<dim3(8, 8, 8), 256, 0, stream>>>(x, vsum);
        for (int b = 0; b < NB; ++b) {
            k_convert<<<4096, 256, 0, stream>>>(x + (size_t)b * elems, Xf, (int)(elems / 4));
            k_gram<<<dim3(136, 1), 256, 0, stream>>>(Xf, G, 0, 0);
            k_attn256<<<dim3(64), 512, 0, stream>>>(Wqf, G, mkey, 0, b);
        }
    }
    k_final<<<32768, 256, 0, stream>>>(vsum, mkey, out);
}

// Round 2
// 496.077 us; speedup vs baseline: 1.0697x; 1.0064x over previous
//
#include <hip/hip_runtime.h>

#define DIM 2048
#define NB 8
#define NT (DIM / 64)   // K-tiles of 64 in the 256^2 8-phase kernel

typedef _Float16 f16;
typedef __attribute__((ext_vector_type(8))) _Float16 f16x8;
typedef __attribute__((ext_vector_type(4))) _Float16 f16x4;
typedef __attribute__((ext_vector_type(2))) _Float16 f16x2;
typedef __attribute__((ext_vector_type(4))) float f32x4;
typedef __attribute__((ext_vector_type(4))) unsigned u32x4;

// ---- float <-> orderable uint key (for atomicMax on floats) ----
__device__ __forceinline__ unsigned fkey(float f) {
    unsigned u = __float_as_uint(f);
    return (u & 0x80000000u) ? ~u : (u | 0x80000000u);
}
__device__ __forceinline__ float fdecode(unsigned k) {
    return (k & 0x80000000u) ? __uint_as_float(k ^ 0x80000000u)
                             : __uint_as_float(~k);
}

// ---- async global->LDS 16B DMA (dest = wave-uniform base + lane*16) ----
__device__ __forceinline__ void gld_lds16(const f16* g, f16* l) {
    __builtin_amdgcn_global_load_lds(
        (const __attribute__((address_space(1))) unsigned*)g,
        (__attribute__((address_space(3))) unsigned*)l, 16, 0, 0);
}

// ---- raw barrier / counted vmcnt discipline ----
// NOTE: no manual lgkmcnt waits in the MFMA loop — the ds_reads are plain C++
// loads, so the compiler emits progressive lgkmcnt(N) before each dependent
// MFMA (m97 evidence). A manual lgkmcnt(0)+sched_barrier here serializes the
// whole read burst against the MFMA cluster (that was R1's 1284cy/phase).
#define BAR() asm volatile("s_barrier" ::: "memory")
#define WAITVM(N) asm volatile("s_waitcnt vmcnt(" #N ")" ::: "memory")

// ---- fp32 -> fp16 conversion, float4 vectorized ----
__global__ __launch_bounds__(256) void k_convert(const float* __restrict__ src,
                                                 f16* __restrict__ dst, int n4) {
    int i = blockIdx.x * 256 + threadIdx.x;
    if (i >= n4) return;
    f32x4 v = ((const f32x4*)src)[i];
    ((f16x4*)dst)[i] = __builtin_convertvector(v, f16x4);
}

// ---- fused: fp32->fp16 convert of x AND column sums over token axis ----
__global__ __launch_bounds__(256) void k_prep(const float* __restrict__ x,
                                              f16* __restrict__ Xf,
                                              float* __restrict__ vsum) {
    const int b  = blockIdx.z;
    const int c0 = blockIdx.x * 1024 + threadIdx.x * 4;
    const int n0 = blockIdx.y * 64;
    const float* px = x  + ((size_t)b * DIM + n0) * DIM + c0;
    f16*         pd = Xf + ((size_t)b * DIM + n0) * DIM + c0;
    f32x4 s = (f32x4){0.f, 0.f, 0.f, 0.f};
    #pragma unroll 8
    for (int n = 0; n < 64; ++n) {
        f32x4 v = *(const f32x4*)(px + (size_t)n * DIM);
        *(f16x4*)(pd + (size_t)n * DIM) = __builtin_convertvector(v, f16x4);
        s += v;
    }
    atomicAdd(&vsum[b * DIM + c0 + 0], s.x);
    atomicAdd(&vsum[b * DIM + c0 + 1], s.y);
    atomicAdd(&vsum[b * DIM + c0 + 2], s.z);
    atomicAdd(&vsum[b * DIM + c0 + 3], s.w);
}

// ---- column sums of x over token axis (fallback paths only) ----
__global__ __launch_bounds__(256) void k_colsum(const float* __restrict__ x,
                                                float* __restrict__ vsum) {
    int b = blockIdx.z;
    int c = blockIdx.x * 256 + threadIdx.x;
    int n0 = blockIdx.y * (DIM / 8);
    const float* p = x + ((size_t)b * DIM + n0) * DIM + c;
    float s = 0.f;
    #pragma unroll 8
    for (int n = 0; n < DIM / 8; ++n) s += p[(size_t)n * DIM];
    atomicAdd(&vsum[b * DIM + c], s);
}

// ---- 128x128 tile core (kept for k_gram): C = A @ Bt^T, f16 ----
__device__ __forceinline__ void gemm128_core(const f16* __restrict__ A,
                                             const f16* __restrict__ Bt,
                                             int br, int bc,
                                             f16* As, f16* Bs,
                                             f32x4 acc[4][4]) {
    const int tid  = threadIdx.x;
    const int ln   = tid & 63;
    const int wv   = tid >> 6;
    const int l15  = ln & 15;
    const int quad = ln >> 4;
    const int wr   = (wv >> 1) * 64;
    const int wc   = (wv & 1) * 64;
    const int lrow = ln >> 3;
    const int lg   = (ln & 7) ^ lrow;
    const int swz  = l15 & 7;

    const f16* gA = A  + (size_t)(br * 128 + wv * 32 + lrow) * DIM + lg * 8;
    const f16* gB = Bt + (size_t)(bc * 128 + wv * 32 + lrow) * DIM + lg * 8;
    f16* lA = As + wv * 2048 + ln * 8;
    f16* lB = Bs + wv * 2048 + ln * 8;

    #pragma unroll
    for (int i = 0; i < 4; ++i)
        #pragma unroll
        for (int j = 0; j < 4; ++j)
            acc[i][j] = (f32x4){0.f, 0.f, 0.f, 0.f};

    for (int kt = 0; kt < DIM / 64; ++kt) {
        __syncthreads();
        #pragma unroll
        for (int u = 0; u < 4; ++u) {
            gld_lds16(gA + (size_t)u * 8 * DIM, lA + u * 512);
            gld_lds16(gB + (size_t)u * 8 * DIM, lB + u * 512);
        }
        gA += 64; gB += 64;
        __syncthreads();
        #pragma unroll
        for (int kk = 0; kk < 2; ++kk) {
            const int s = (kk * 4 + quad) ^ swz;
            f16x8 af[4], bf[4];
            #pragma unroll
            for (int i = 0; i < 4; ++i)
                af[i] = *(const f16x8*)(As + (wr + i * 16 + l15) * 64 + s * 8);
            #pragma unroll
            for (int j = 0; j < 4; ++j)
                bf[j] = *(const f16x8*)(Bs + (wc + j * 16 + l15) * 64 + s * 8);
            #pragma unroll
            for (int i = 0; i < 4; ++i)
                #pragma unroll
                for (int j = 0; j < 4; ++j)
                    acc[i][j] = __builtin_amdgcn_mfma_f32_16x16x32_f16(af[i], bf[j], acc[i][j], 0, 0, 0);
        }
    }
}

// ---- Gram: G_b = X_b @ X_b^T (symmetric; triangular grid, LDS-transposed mirror) ----
__global__ __launch_bounds__(256) void k_gram(const f16* __restrict__ Xall,
                                              f16* __restrict__ Gall,
                                              unsigned long xStride,
                                              unsigned long gStride) {
    const int b = blockIdx.y;
    const f16* X = Xall + (size_t)b * xStride;
    f16* G = Gall + (size_t)b * gStride;

    int t = blockIdx.x;
    int br = (int)((sqrtf(8.f * t + 1.f) - 1.f) * 0.5f);
    while ((br + 1) * (br + 2) / 2 <= t) ++br;
    while (br * (br + 1) / 2 > t) --br;
    int bc = t - br * (br + 1) / 2;

    __shared__ __align__(16) f16 smem[128 * 136];
    f16* As = smem;
    f16* Bs = smem + 8192;
    f32x4 acc[4][4];
    gemm128_core(X, X, br, bc, As, Bs, acc);

    const int tid = threadIdx.x;
    const int ln = tid & 63;
    const int wv = tid >> 6;
    const int wr = (wv >> 1) * 64, wc = (wv & 1) * 64;
    const int l15 = ln & 15, quad = ln >> 4;

    #pragma unroll
    for (int i = 0; i < 4; ++i)
        #pragma unroll
        for (int j = 0; j < 4; ++j)
            #pragma unroll
            for (int r = 0; r < 4; ++r) {
                int row = br * 128 + wr + i * 16 + quad * 4 + r;
                int col = bc * 128 + wc + j * 16 + l15;
                G[(size_t)row * DIM + col] = (f16)acc[i][j][r];
            }

    if (br != bc) {
        __syncthreads();
        f16* T = smem;
        #pragma unroll
        for (int i = 0; i < 4; ++i)
            #pragma unroll
            for (int j = 0; j < 4; ++j)
                #pragma unroll
                for (int h = 0; h < 2; ++h) {
                    int row = wr + i * 16 + quad * 4 + h * 2;
                    int col = wc + j * 16 + l15;
                    f16x2 v = {(f16)acc[i][j][h * 2], (f16)acc[i][j][h * 2 + 1]};
                    *(f16x2*)(T + col * 136 + row) = v;
                }
        __syncthreads();
        #pragma unroll
        for (int p = 0; p < 8; ++p) {
            int ch = p * 256 + tid;
            int rt = ch >> 4, seg = ch & 15;
            f16x8 v = *(const f16x8*)(T + rt * 136 + seg * 8);
            *(f16x8*)(G + (size_t)(bc * 128 + rt) * DIM + br * 128 + seg * 8) = v;
        }
    }
}

// ---- attn tile = scale * Wq @ G_b  (256^2 tile, BK=64, 8 waves, 4-phase
//      counted-vmcnt schedule, compiler-managed progressive lgkmcnt;
//      fused row-max via shfl + atomicMax) ----
// Hazard audit (one closing barrier per phase):
//   stage(t+2,S0) [P1] vs A-low reads  (done < P0 MFMA < P0 BAR)   : 1 bar  OK
//   stage(t+2,S1) [P2] vs bl reads     (done < P0 MFMA < P0 BAR)   : 2 bars OK
//   stage(t+2,S2) [P3] vs bh reads     (done < P1 MFMA < P1 BAR)   : 2 bars OK
//   stage(t+1,S3) [P0] vs A-high reads of t-1 (done < P2(t-1) BAR) : 2 bars OK
//   publish of tile t+1: WAITVM(6)+BAR at end of P3                : OK
__global__ __launch_bounds__(512, 2)
void k_attn256(const f16* __restrict__ Wq, const f16* __restrict__ Gall,
               unsigned* __restrict__ mkey, unsigned long gStride, int batchBase) {
    __shared__ __align__(16) f16 sm[2][2][256 * 64];   // [buf][op A/B][row*chunk] = 128 KiB

    const int q  = gridDim.x >> 3;
    const int w  = (blockIdx.x & 7) * q + (blockIdx.x >> 3);   // XCD-chunked, bijective
    const int zi = w >> 6;
    const int br = (w >> 3) & 7;
    const int bc = w & 7;
    const f16* A  = Wq;
    const f16* Bt = Gall + (size_t)zi * gStride;   // G symmetric: rows serve as Bt rows
    const int bi = batchBase + zi;

    const int tid  = threadIdx.x;
    const int ln   = tid & 63;
    const int wv   = tid >> 6;
    const int wm   = wv >> 2;
    const int wn   = wv & 3;
    const int l15  = ln & 15;
    const int quad = ln >> 4;
    const int swz  = l15 & 7;
    const int cc0  = ((quad) ^ swz) * 8;
    const int cc1  = ((4 | quad) ^ swz) * 8;
    const int lrow = ln >> 3;
    const int lchunk = (ln & 7) ^ lrow;

    f32x4 acc[8][4];
    #pragma unroll
    for (int i = 0; i < 8; ++i)
        #pragma unroll
        for (int j = 0; j < 4; ++j) acc[i][j] = (f32x4){0.f, 0.f, 0.f, 0.f};

    auto stage = [&](int t, int s) {
        if (t >= NT) return;
        const int p = t & 1;
        const f16* src; int rowb; f16* L;
        if (s == 0 || s == 3) { src = A;  rowb = br * 256; L = (f16*)sm[p][0]; }
        else                  { src = Bt; rowb = bc * 256; L = (f16*)sm[p][1]; }
        const int h  = (s >= 2) ? 1 : 0;
        const int r0 = h * 128 + wv * 16;
        const f16* gp = src + (size_t)(rowb + r0 + lrow) * DIM + t * 64 + lchunk * 8;
        f16* lp = L + r0 * 64 + ln * 8;
        gld_lds16(gp, lp);
        gld_lds16(gp + (size_t)8 * DIM, lp + 512);
    };

    f16x8 af[4][2], bl[2][2], bh[2][2];

    auto loadA = [&](int qm, const f16* LA) {
        #pragma unroll
        for (int i = 0; i < 4; ++i) {
            const f16* pa = LA + (qm * 128 + wm * 64 + i * 16 + l15) * 64;
            af[i][0] = *(const f16x8*)(pa + cc0);
            af[i][1] = *(const f16x8*)(pa + cc1);
        }
    };
    auto loadB = [&](int qn, const f16* LB, f16x8 (&bf)[2][2]) {
        #pragma unroll
        for (int j = 0; j < 2; ++j) {
            const f16* pb = LB + (qn * 128 + wn * 32 + j * 16 + l15) * 64;
            bf[j][0] = *(const f16x8*)(pb + cc0);
            bf[j][1] = *(const f16x8*)(pb + cc1);
        }
    };
    auto mfmaQ = [&](int qm, int qn, f16x8 (&a)[4][2], f16x8 (&bf)[2][2]) {
        __builtin_amdgcn_s_setprio(1);
        #pragma unroll
        for (int i = 0; i < 4; ++i)
            #pragma unroll
            for (int j = 0; j < 2; ++j)
                #pragma unroll
                for (int kk = 0; kk < 2; ++kk)
                    acc[qm * 4 + i][qn * 2 + j] = __builtin_amdgcn_mfma_f32_16x16x32_f16(
                        a[i][kk], bf[j][kk], acc[qm * 4 + i][qn * 2 + j], 0, 0, 0);
        __builtin_amdgcn_s_setprio(0);
    };

    // prologue: tile 0 complete + 3/4 of tile 1 in flight
    stage(0, 0); stage(0, 1); stage(0, 2); stage(0, 3);
    WAITVM(4);
    stage(1, 0); stage(1, 1); stage(1, 2);
    WAITVM(6);
    BAR();

    for (int t = 0; t < NT; ++t) {
        const f16* LA = (const f16*)sm[t & 1][0];
        const f16* LB = (const f16*)sm[t & 1][1];
        // P0: all Q0/Q1 reads up front (bh prefetched; compiler waits af+bl only)
        loadA(0, LA); loadB(0, LB, bl); loadB(1, LB, bh);
        stage(t + 1, 3);
        mfmaQ(0, 0, af, bl);
        BAR();
        // P1: zero reads — bh landed under P0's MFMA
        stage(t + 2, 0);
        mfmaQ(0, 1, af, bh);
        BAR();
        // P2: A-high reload (WAR on af after P1's MFMA; compiler orders it)
        loadA(1, LA);
        stage(t + 2, 1);
        mfmaQ(1, 1, af, bh);
        BAR();
        // P3: register-only MFMA; tile t+1 publish
        stage(t + 2, 2);
        mfmaQ(1, 0, af, bl);
        if (t < NT - 2) { WAITVM(6); }
        else            { WAITVM(0); }
        BAR();
    }

    const float scale = 0.0625f;              // (2048/8)^-0.5
    #pragma unroll
    for (int i = 0; i < 8; ++i) {
        const int qm = i >> 2, il = i & 3;
        #pragma unroll
        for (int r = 0; r < 4; ++r) {
            float v = fmaxf(fmaxf(acc[i][0][r], acc[i][1][r]),
                            fmaxf(acc[i][2][r], acc[i][3][r]));
            #pragma unroll
            for (int m = 1; m <= 8; m <<= 1)
                v = fmaxf(v, __shfl_xor(v, m, 64));
            if (l15 == 0) {
                const int row = br * 256 + qm * 128 + wm * 64 + il * 16 + quad * 4 + r;
                atomicMax(&mkey[(size_t)bi * DIM + row], fkey(scale * v));
            }
        }
    }
}

// ---- out[b,i,j] = (vsum[b,i]/2048) * m[b,j] ----
__global__ __launch_bounds__(256) void k_final(const float* __restrict__ vsum,
                                               const unsigned* __restrict__ mkey,
                                               float* __restrict__ out) {
    int gid = blockIdx.x * 256 + threadIdx.x;
    int b   = gid >> 20;
    int rem = gid & 1048575;
    int i   = rem >> 9;
    int jq  = rem & 511;
    float v = vsum[(b << 11) + i] * (1.f / 2048.f);
    u32x4 k = ((const u32x4*)mkey)[(b << 9) + jq];
    f32x4 o;
    o.x = v * fdecode(k.x);
    o.y = v * fdecode(k.y);
    o.z = v * fdecode(k.z);
    o.w = v * fdecode(k.w);
    ((f32x4*)out)[gid] = o;
}

extern "C" void kernel_launch(void* const* d_in, const int* in_sizes, int n_in,
                              void* d_out, int out_size, void* d_ws, size_t ws_size,
                              hipStream_t stream) {
    const float* x  = (const float*)d_in[0];
    const float* Wq = (const float*)d_in[1];
    float* out = (float*)d_out;
    char* ws = (char*)d_ws;

    const size_t elems = (size_t)DIM * DIM;
    unsigned* mkey = (unsigned*)ws;                         // 64 KB
    float*    vsum = (float*)(ws + 65536);                  // 64 KB
    f16*      Wqf  = (f16*)(ws + 131072);                   // 8 MB
    f16*      Xf   = (f16*)(ws + 131072 + elems * 2);

    const size_t need1 = 131072 + elems * 2 * (1 + NB + NB);  // ~142.7 MB
    const size_t need2 = 131072 + elems * 2 * (1 + NB + 1);   // ~84.0 MB

    hipMemsetAsync(ws, 0, 131072, stream);
    k_convert<<<4096, 256, 0, stream>>>(Wq, Wqf, (int)(elems / 4));

    if (ws_size >= need1) {
        f16* G = Xf + NB * elems;
        k_prep<<<dim3(2, 32, NB), 256, 0, stream>>>(x, Xf, vsum);
        k_gram<<<dim3(136, NB), 256, 0, stream>>>(Xf, G, elems, elems);
        k_attn256<<<dim3(512), 512, 0, stream>>>(Wqf, G, mkey, elems, 0);
    } else if (ws_size >= need2) {
        f16* G = Xf + NB * elems;
        k_prep<<<dim3(2, 32, NB), 256, 0, stream>>>(x, Xf, vsum);
        for (int b = 0; b < NB; ++b) {
            k_gram<<<dim3(136, 1), 256, 0, stream>>>(Xf + (size_t)b * elems, G, 0, 0);
            k_attn256<<<dim3(64), 512, 0, stream>>>(Wqf, G, mkey, 0, b);
        }
    } else {
        f16* G = Xf + elems;
        k_colsum<<<dim3(8, 8, 8), 256, 0, stream>>>(x, vsum);
        for (int b = 0; b < NB; ++b) {
            k_convert<<<4096, 256, 0, stream>>>(x + (size_t)b * elems, Xf, (int)(elems / 4));
            k_gram<<<dim3(136, 1), 256, 0, stream>>>(Xf, G, 0, 0);
            k_attn256<<<dim3(64), 512, 0, stream>>>(Wqf, G, mkey, 0, b);
        }
    }
    k_final<<<32768, 256, 0, stream>>>(vsum, mkey, out);
}

// Round 3
// 485.413 us; speedup vs baseline: 1.0932x; 1.0220x over previous
//
#include <hip/hip_runtime.h>

#define DIM 2048
#define NB 8
#define NT (DIM / 64)   // K-tiles of 64 in the 256^2 kernel

typedef _Float16 f16;
typedef __attribute__((ext_vector_type(8))) _Float16 f16x8;
typedef __attribute__((ext_vector_type(4))) _Float16 f16x4;
typedef __attribute__((ext_vector_type(2))) _Float16 f16x2;
typedef __attribute__((ext_vector_type(4))) float f32x4;
typedef __attribute__((ext_vector_type(4))) unsigned u32x4;

// ---- float <-> orderable uint key (for atomicMax on floats) ----
__device__ __forceinline__ unsigned fkey(float f) {
    unsigned u = __float_as_uint(f);
    return (u & 0x80000000u) ? ~u : (u | 0x80000000u);
}
__device__ __forceinline__ float fdecode(unsigned k) {
    return (k & 0x80000000u) ? __uint_as_float(k ^ 0x80000000u)
                             : __uint_as_float(~k);
}

// ---- async global->LDS 16B DMA (dest = wave-uniform base + lane*16) ----
__device__ __forceinline__ void gld_lds16(const f16* g, f16* l) {
    __builtin_amdgcn_global_load_lds(
        (const __attribute__((address_space(1))) unsigned*)g,
        (__attribute__((address_space(3))) unsigned*)l, 16, 0, 0);
}

// ---- raw barrier / counted vmcnt ----
// Two lockstep points per K-tile (not four): each BAR's "memory" clobber pins
// ds_reads into their phase, so barrier count == pipelining granularity.
#define BAR() asm volatile("s_barrier" ::: "memory")
#define WAITVM(N) asm volatile("s_waitcnt vmcnt(" #N ")" ::: "memory")

// ---- fp32 -> fp16 conversion, float4 vectorized ----
__global__ __launch_bounds__(256) void k_convert(const float* __restrict__ src,
                                                 f16* __restrict__ dst, int n4) {
    int i = blockIdx.x * 256 + threadIdx.x;
    if (i >= n4) return;
    f32x4 v = ((const f32x4*)src)[i];
    ((f16x4*)dst)[i] = __builtin_convertvector(v, f16x4);
}

// ---- fused: fp32->fp16 convert of x AND column sums over token axis ----
__global__ __launch_bounds__(256) void k_prep(const float* __restrict__ x,
                                              f16* __restrict__ Xf,
                                              float* __restrict__ vsum) {
    const int b  = blockIdx.z;
    const int c0 = blockIdx.x * 1024 + threadIdx.x * 4;
    const int n0 = blockIdx.y * 64;
    const float* px = x  + ((size_t)b * DIM + n0) * DIM + c0;
    f16*         pd = Xf + ((size_t)b * DIM + n0) * DIM + c0;
    f32x4 s = (f32x4){0.f, 0.f, 0.f, 0.f};
    #pragma unroll 8
    for (int n = 0; n < 64; ++n) {
        f32x4 v = *(const f32x4*)(px + (size_t)n * DIM);
        *(f16x4*)(pd + (size_t)n * DIM) = __builtin_convertvector(v, f16x4);
        s += v;
    }
    atomicAdd(&vsum[b * DIM + c0 + 0], s.x);
    atomicAdd(&vsum[b * DIM + c0 + 1], s.y);
    atomicAdd(&vsum[b * DIM + c0 + 2], s.z);
    atomicAdd(&vsum[b * DIM + c0 + 3], s.w);
}

// ---- column sums of x over token axis (fallback paths only) ----
__global__ __launch_bounds__(256) void k_colsum(const float* __restrict__ x,
                                                float* __restrict__ vsum) {
    int b = blockIdx.z;
    int c = blockIdx.x * 256 + threadIdx.x;
    int n0 = blockIdx.y * (DIM / 8);
    const float* p = x + ((size_t)b * DIM + n0) * DIM + c;
    float s = 0.f;
    #pragma unroll 8
    for (int n = 0; n < DIM / 8; ++n) s += p[(size_t)n * DIM];
    atomicAdd(&vsum[b * DIM + c], s);
}

// ---- 128x128 tile core (kept for k_gram): C = A @ Bt^T, f16 ----
__device__ __forceinline__ void gemm128_core(const f16* __restrict__ A,
                                             const f16* __restrict__ Bt,
                                             int br, int bc,
                                             f16* As, f16* Bs,
                                             f32x4 acc[4][4]) {
    const int tid  = threadIdx.x;
    const int ln   = tid & 63;
    const int wv   = tid >> 6;
    const int l15  = ln & 15;
    const int quad = ln >> 4;
    const int wr   = (wv >> 1) * 64;
    const int wc   = (wv & 1) * 64;
    const int lrow = ln >> 3;
    const int lg   = (ln & 7) ^ lrow;
    const int swz  = l15 & 7;

    const f16* gA = A  + (size_t)(br * 128 + wv * 32 + lrow) * DIM + lg * 8;
    const f16* gB = Bt + (size_t)(bc * 128 + wv * 32 + lrow) * DIM + lg * 8;
    f16* lA = As + wv * 2048 + ln * 8;
    f16* lB = Bs + wv * 2048 + ln * 8;

    #pragma unroll
    for (int i = 0; i < 4; ++i)
        #pragma unroll
        for (int j = 0; j < 4; ++j)
            acc[i][j] = (f32x4){0.f, 0.f, 0.f, 0.f};

    for (int kt = 0; kt < DIM / 64; ++kt) {
        __syncthreads();
        #pragma unroll
        for (int u = 0; u < 4; ++u) {
            gld_lds16(gA + (size_t)u * 8 * DIM, lA + u * 512);
            gld_lds16(gB + (size_t)u * 8 * DIM, lB + u * 512);
        }
        gA += 64; gB += 64;
        __syncthreads();
        #pragma unroll
        for (int kk = 0; kk < 2; ++kk) {
            const int s = (kk * 4 + quad) ^ swz;
            f16x8 af[4], bf[4];
            #pragma unroll
            for (int i = 0; i < 4; ++i)
                af[i] = *(const f16x8*)(As + (wr + i * 16 + l15) * 64 + s * 8);
            #pragma unroll
            for (int j = 0; j < 4; ++j)
                bf[j] = *(const f16x8*)(Bs + (wc + j * 16 + l15) * 64 + s * 8);
            #pragma unroll
            for (int i = 0; i < 4; ++i)
                #pragma unroll
                for (int j = 0; j < 4; ++j)
                    acc[i][j] = __builtin_amdgcn_mfma_f32_16x16x32_f16(af[i], bf[j], acc[i][j], 0, 0, 0);
        }
    }
}

// ---- Gram: G_b = X_b @ X_b^T (symmetric; triangular grid, LDS-transposed mirror) ----
__global__ __launch_bounds__(256) void k_gram(const f16* __restrict__ Xall,
                                              f16* __restrict__ Gall,
                                              unsigned long xStride,
                                              unsigned long gStride) {
    const int b = blockIdx.y;
    const f16* X = Xall + (size_t)b * xStride;
    f16* G = Gall + (size_t)b * gStride;

    int t = blockIdx.x;
    int br = (int)((sqrtf(8.f * t + 1.f) - 1.f) * 0.5f);
    while ((br + 1) * (br + 2) / 2 <= t) ++br;
    while (br * (br + 1) / 2 > t) --br;
    int bc = t - br * (br + 1) / 2;

    __shared__ __align__(16) f16 smem[128 * 136];
    f16* As = smem;
    f16* Bs = smem + 8192;
    f32x4 acc[4][4];
    gemm128_core(X, X, br, bc, As, Bs, acc);

    const int tid = threadIdx.x;
    const int ln = tid & 63;
    const int wv = tid >> 6;
    const int wr = (wv >> 1) * 64, wc = (wv & 1) * 64;
    const int l15 = ln & 15, quad = ln >> 4;

    #pragma unroll
    for (int i = 0; i < 4; ++i)
        #pragma unroll
        for (int j = 0; j < 4; ++j)
            #pragma unroll
            for (int r = 0; r < 4; ++r) {
                int row = br * 128 + wr + i * 16 + quad * 4 + r;
                int col = bc * 128 + wc + j * 16 + l15;
                G[(size_t)row * DIM + col] = (f16)acc[i][j][r];
            }

    if (br != bc) {
        __syncthreads();
        f16* T = smem;
        #pragma unroll
        for (int i = 0; i < 4; ++i)
            #pragma unroll
            for (int j = 0; j < 4; ++j)
                #pragma unroll
                for (int h = 0; h < 2; ++h) {
                    int row = wr + i * 16 + quad * 4 + h * 2;
                    int col = wc + j * 16 + l15;
                    f16x2 v = {(f16)acc[i][j][h * 2], (f16)acc[i][j][h * 2 + 1]};
                    *(f16x2*)(T + col * 136 + row) = v;
                }
        __syncthreads();
        #pragma unroll
        for (int p = 0; p < 8; ++p) {
            int ch = p * 256 + tid;
            int rt = ch >> 4, seg = ch & 15;
            f16x8 v = *(const f16x8*)(T + rt * 136 + seg * 8);
            *(f16x8*)(G + (size_t)(bc * 128 + rt) * DIM + br * 128 + seg * 8) = v;
        }
    }
}

// ---- attn tile = scale * Wq @ G_b  (256^2 tile, BK=64, 8 waves, TWO-phase
//      schedule: 32 MFMA per lockstep window, counted vmcnt; fused row-max) ----
// PhX: reads {A-low(8), B-low(4), B-high(4)}, stage (t+1,S3), MFMA Q00,Q01.
// PhY: reads {A-high(8) into same regs}, stage (t+2,S0..S2), MFMA Q10,Q11,
//      WAITVM(6) -> publishes tile t+1 (oldest 8 of 14 outstanding), BAR.
// Region audit: all buf-bt stages sit in PhY, one barrier after PhX's reads of
// those regions; (t+1,S3)->A-high(bn) is >=1 barrier after af2(t-1) reads.
__global__ __launch_bounds__(512, 2)
void k_attn256(const f16* __restrict__ Wq, const f16* __restrict__ Gall,
               unsigned* __restrict__ mkey, unsigned long gStride, int batchBase) {
    __shared__ __align__(16) f16 sm[2][2][256 * 64];   // [buf][op A/B][row*chunk] = 128 KiB

    const int q  = gridDim.x >> 3;
    const int w  = (blockIdx.x & 7) * q + (blockIdx.x >> 3);   // XCD-chunked, bijective
    const int zi = w >> 6;
    const int br = (w >> 3) & 7;
    const int bc = w & 7;
    const f16* A  = Wq;
    const f16* Bt = Gall + (size_t)zi * gStride;   // G symmetric: rows serve as Bt rows
    const int bi = batchBase + zi;

    const int tid  = threadIdx.x;
    const int ln   = tid & 63;
    const int wv   = tid >> 6;
    const int wm   = wv >> 2;
    const int wn   = wv & 3;
    const int l15  = ln & 15;
    const int quad = ln >> 4;
    const int swz  = l15 & 7;
    const int cc0  = ((quad) ^ swz) * 8;
    const int cc1  = ((4 | quad) ^ swz) * 8;
    const int lrow = ln >> 3;
    const int lchunk = (ln & 7) ^ lrow;

    f32x4 acc[8][4];
    #pragma unroll
    for (int i = 0; i < 8; ++i)
        #pragma unroll
        for (int j = 0; j < 4; ++j) acc[i][j] = (f32x4){0.f, 0.f, 0.f, 0.f};

    auto stage = [&](int t, int s) {
        if (t >= NT) return;
        const int p = t & 1;
        const f16* src; int rowb; f16* L;
        if (s == 0 || s == 3) { src = A;  rowb = br * 256; L = (f16*)sm[p][0]; }
        else                  { src = Bt; rowb = bc * 256; L = (f16*)sm[p][1]; }
        const int h  = (s >= 2) ? 1 : 0;
        const int r0 = h * 128 + wv * 16;
        const f16* gp = src + (size_t)(rowb + r0 + lrow) * DIM + t * 64 + lchunk * 8;
        f16* lp = L + r0 * 64 + ln * 8;
        gld_lds16(gp, lp);
        gld_lds16(gp + (size_t)8 * DIM, lp + 512);
    };

    f16x8 af[4][2], bl[2][2], bh[2][2];

    auto loadA = [&](int qm, const f16* LA) {
        #pragma unroll
        for (int i = 0; i < 4; ++i) {
            const f16* pa = LA + (qm * 128 + wm * 64 + i * 16 + l15) * 64;
            af[i][0] = *(const f16x8*)(pa + cc0);
            af[i][1] = *(const f16x8*)(pa + cc1);
        }
    };
    auto loadB = [&](int qn, const f16* LB, f16x8 (&bf)[2][2]) {
        #pragma unroll
        for (int j = 0; j < 2; ++j) {
            const f16* pb = LB + (qn * 128 + wn * 32 + j * 16 + l15) * 64;
            bf[j][0] = *(const f16x8*)(pb + cc0);
            bf[j][1] = *(const f16x8*)(pb + cc1);
        }
    };
    auto mfmaQ = [&](int qm, int qn, f16x8 (&a)[4][2], f16x8 (&bf)[2][2]) {
        __builtin_amdgcn_s_setprio(1);
        #pragma unroll
        for (int i = 0; i < 4; ++i)
            #pragma unroll
            for (int j = 0; j < 2; ++j)
                #pragma unroll
                for (int kk = 0; kk < 2; ++kk)
                    acc[qm * 4 + i][qn * 2 + j] = __builtin_amdgcn_mfma_f32_16x16x32_f16(
                        a[i][kk], bf[j][kk], acc[qm * 4 + i][qn * 2 + j], 0, 0, 0);
        __builtin_amdgcn_s_setprio(0);
    };

    // prologue: tile 0 complete + 3/4 of tile 1 in flight
    stage(0, 0); stage(0, 1); stage(0, 2); stage(0, 3);
    WAITVM(4);
    stage(1, 0); stage(1, 1); stage(1, 2);
    WAITVM(6);
    BAR();

    for (int t = 0; t < NT; ++t) {
        const f16* LA = (const f16*)sm[t & 1][0];
        const f16* LB = (const f16*)sm[t & 1][1];
        // ---- PhX: 16 reads (Q00 deps first, bh last lands under Q00) + 32 MFMA
        loadA(0, LA); loadB(0, LB, bl); loadB(1, LB, bh);
        stage(t + 1, 3);                       // A-high(bn): af2(t-1) read >=1 bar ago
        mfmaQ(0, 0, af, bl);
        mfmaQ(0, 1, af, bh);
        BAR();
        // ---- PhY: 8 reads (A-high into af regs) + 32 MFMA + publish t+1
        loadA(1, LA);
        stage(t + 2, 0); stage(t + 2, 1); stage(t + 2, 2);  // all buf-bt regions, read in PhX
        mfmaQ(1, 0, af, bl);
        mfmaQ(1, 1, af, bh);
        if (t < NT - 2) { WAITVM(6); }         // drains (t+1,S0..S3); 6 stay in flight
        else            { WAITVM(0); }         // prefetch stream ended: full drain
        BAR();
    }

    const float scale = 0.0625f;              // (2048/8)^-0.5
    #pragma unroll
    for (int i = 0; i < 8; ++i) {
        const int qm = i >> 2, il = i & 3;
        #pragma unroll
        for (int r = 0; r < 4; ++r) {
            float v = fmaxf(fmaxf(acc[i][0][r], acc[i][1][r]),
                            fmaxf(acc[i][2][r], acc[i][3][r]));
            #pragma unroll
            for (int m = 1; m <= 8; m <<= 1)
                v = fmaxf(v, __shfl_xor(v, m, 64));
            if (l15 == 0) {
                const int row = br * 256 + qm * 128 + wm * 64 + il * 16 + quad * 4 + r;
                atomicMax(&mkey[(size_t)bi * DIM + row], fkey(scale * v));
            }
        }
    }
}

// ---- out[b,i,j] = (vsum[b,i]/2048) * m[b,j] ----
__global__ __launch_bounds__(256) void k_final(const float* __restrict__ vsum,
                                               const unsigned* __restrict__ mkey,
                                               float* __restrict__ out) {
    int gid = blockIdx.x * 256 + threadIdx.x;
    int b   = gid >> 20;
    int rem = gid & 1048575;
    int i   = rem >> 9;
    int jq  = rem & 511;
    float v = vsum[(b << 11) + i] * (1.f / 2048.f);
    u32x4 k = ((const u32x4*)mkey)[(b << 9) + jq];
    f32x4 o;
    o.x = v * fdecode(k.x);
    o.y = v * fdecode(k.y);
    o.z = v * fdecode(k.z);
    o.w = v * fdecode(k.w);
    ((f32x4*)out)[gid] = o;
}

extern "C" void kernel_launch(void* const* d_in, const int* in_sizes, int n_in,
                              void* d_out, int out_size, void* d_ws, size_t ws_size,
                              hipStream_t stream) {
    const float* x  = (const float*)d_in[0];
    const float* Wq = (const float*)d_in[1];
    float* out = (float*)d_out;
    char* ws = (char*)d_ws;

    const size_t elems = (size_t)DIM * DIM;
    unsigned* mkey = (unsigned*)ws;                         // 64 KB
    float*    vsum = (float*)(ws + 65536);                  // 64 KB
    f16*      Wqf  = (f16*)(ws + 131072);                   // 8 MB
    f16*      Xf   = (f16*)(ws + 131072 + elems * 2);

    const size_t need1 = 131072 + elems * 2 * (1 + NB + NB);  // ~142.7 MB
    const size_t need2 = 131072 + elems * 2 * (1 + NB + 1);   // ~84.0 MB

    hipMemsetAsync(ws, 0, 131072, stream);
    k_convert<<<4096, 256, 0, stream>>>(Wq, Wqf, (int)(elems / 4));

    if (ws_size >= need1) {
        f16* G = Xf + NB * elems;
        k_prep<<<dim3(2, 32, NB), 256, 0, stream>>>(x, Xf, vsum);
        k_gram<<<dim3(136, NB), 256, 0, stream>>>(Xf, G, elems, elems);
        k_attn256<<<dim3(512), 512, 0, stream>>>(Wqf, G, mkey, elems, 0);
    } else if (ws_size >= need2) {
        f16* G = Xf + NB * elems;
        k_prep<<<dim3(2, 32, NB), 256, 0, stream>>>(x, Xf, vsum);
        for (int b = 0; b < NB; ++b) {
            k_gram<<<dim3(136, 1), 256, 0, stream>>>(Xf + (size_t)b * elems, G, 0, 0);
            k_attn256<<<dim3(64), 512, 0, stream>>>(Wqf, G, mkey, 0, b);
        }
    } else {
        f16* G = Xf + elems;
        k_colsum<<<dim3(8, 8, 8), 256, 0, stream>>>(x, vsum);
        for (int b = 0; b < NB; ++b) {
            k_convert<<<4096, 256, 0, stream>>>(x + (size_t)b * elems, Xf, (int)(elems / 4));
            k_gram<<<dim3(136, 1), 256, 0, stream>>>(Xf, G, 0, 0);
            k_attn256<<<dim3(64), 512, 0, stream>>>(Wqf, G, mkey, 0, b);
        }
    }
    k_final<<<32768, 256, 0, stream>>>(vsum, mkey, out);
}